// Round 9
// baseline (903.871 us; speedup 1.0000x reference)
//
#include <hip/hip_runtime.h>

// Problem constants (fixed by the reference).
#define NNODES 100000
#define NEDGES 800000
#define DIN    128
#define HID    64
#define EMB    32
#define NIDX   50000
#define BN_EPS 1e-5f

#define NCHK 64                   // partition chunks (write-amp: ~8-edge runs)
#define EC   (NEDGES / NCHK)      // 12500 edges per chunk
#define SUBC 256                  // histogram sub-chunks (parallelism)
#define ECS  (NEDGES / SUBC)      // 3125 edges per sub-chunk
#define NB   ((NNODES + 63) / 64) // 1563 row-buckets of 64 rows

typedef __attribute__((ext_vector_type(8))) short short8;   // 8 bf16 = 4 VGPR
typedef __attribute__((ext_vector_type(4))) float f32x4;    // MFMA C/D

__device__ inline unsigned short f2bf(float f) {            // RNE, matches HW
    unsigned u = __float_as_uint(f);
    unsigned r = u + 0x7FFFu + ((u >> 16) & 1u);
    return (unsigned short)(r >> 16);
}
__device__ inline float bf2f_lo(unsigned u) { return __uint_as_float(u << 16); }
__device__ inline float bf2f_hi(unsigned u) { return __uint_as_float(u & 0xffff0000u); }

// ---------------------------------------------------------------------------
// W pre-pack (all three layers): fp32 [Wn|Wg] -> bf16 B-fragment-major.
// ---------------------------------------------------------------------------

__device__ inline void pack_seg(const float* __restrict__ Wn, const float* __restrict__ Wg,
                                unsigned short* __restrict__ Wp, int HOUT, int l2nt, int f) {
    int j = f & 7, lane = (f >> 3) & 63, g = f >> 9;
    int tt = g & ((1 << l2nt) - 1), kb = g >> l2nt;
    int k = kb * 32 + ((lane >> 4) * 8) + j;
    int nn = tt * 16 + (lane & 15);
    float v = (nn < HOUT) ? Wn[k * HOUT + nn] : Wg[k * HOUT + (nn - HOUT)];
    Wp[f] = f2bf(v);
}

__global__ void packall_k(const float* Wn0, const float* Wg0, const float* Wn1,
                          const float* Wg1, const float* WnL, const float* WgL,
                          unsigned short* Wp0, unsigned short* Wp1, unsigned short* WpL) {
    int f = blockIdx.x * 256 + threadIdx.x;
    if (f < 16384)      pack_seg(Wn0, Wg0, Wp0, 64, 3, f);           // 128x128
    else if (f < 24576) pack_seg(Wn1, Wg1, Wp1, 64, 3, f - 16384);   // 64x128
    else if (f < 28672) pack_seg(WnL, WgL, WpL, 32, 2, f - 24576);   // 64x64
}

// ---------------------------------------------------------------------------
// Bucket partition (atomic-free globally, LDS atomics only).
// bhist: 256 sub-chunk blocks histogram bucket=row>>6 -> Bcnt4[sub][b]
//        (+196 blocks: mark[idx[j]]=1).
// bprefix: per bucket, run over 256 subs (coalesced [sub][b] layout);
//          emit per-partition-chunk exclusive prefix BcntT[chunk][b] + totals.
// bscan: exclusive scan of 1563 bucket totals -> bBase.
// ---------------------------------------------------------------------------

__global__ __launch_bounds__(256) void bhist_k(const int* __restrict__ rows,
                                               int* __restrict__ Bcnt4,
                                               const int* __restrict__ idx,
                                               int* __restrict__ mark) {
    if ((int)blockIdx.x >= SUBC) {
        int j = ((int)blockIdx.x - SUBC) * 256 + threadIdx.x;
        if (j < NIDX) mark[idx[j]] = 1;
        return;
    }
    __shared__ int hist[NB];
    int t = threadIdx.x, blk = blockIdx.x;
    for (int b = t; b < NB; b += 256) hist[b] = 0;
    __syncthreads();
    for (int i = t; i < ECS; i += 256)
        atomicAdd(&hist[rows[blk * ECS + i] >> 6], 1);
    __syncthreads();
    for (int b = t; b < NB; b += 256) Bcnt4[blk * NB + b] = hist[b];
}

__global__ void bprefix_k(const int* __restrict__ Bcnt4, int* __restrict__ BcntT,
                          int* __restrict__ bTot) {
    int b = blockIdx.x * 256 + threadIdx.x;
    if (b >= NB) return;
    int run = 0;
    for (int sub = 0; sub < SUBC; sub++) {
        if ((sub & 3) == 0) BcntT[(sub >> 2) * NB + b] = run;  // chunk = sub/4
        run += Bcnt4[sub * NB + b];                            // coalesced
    }
    bTot[b] = run;
}

__global__ void bscan_k(const int* __restrict__ bTot, int* __restrict__ bBase) {
    __shared__ int s[256];
    int t = threadIdx.x;
    int v[7], loc = 0;
#pragma unroll
    for (int i = 0; i < 7; i++) {
        int ix = t * 7 + i;
        v[i] = loc;
        loc += (ix < NB) ? bTot[ix] : 0;
    }
    s[t] = loc;
    __syncthreads();
    for (int off = 1; off < 256; off <<= 1) {
        int a = (t >= off) ? s[t - off] : 0;
        __syncthreads();
        s[t] += a;
        __syncthreads();
    }
    int base = s[t] - loc;
#pragma unroll
    for (int i = 0; i < 7; i++) {
        int ix = t * 7 + i;
        if (ix < NB) bBase[ix] = base + v[i];
    }
    if (t == 255) bBase[NB] = NEDGES;
}

// ---------------------------------------------------------------------------
// MFMA dual-GEMM body. [Hn | Hg] = act(X) @ [Wn | Wg] (+ per-col biases);
// Hg always bf16 out; Hn bf16 (HNBF) or fp32. X fp32 or bf16 (XBF).
// AFF: BN scale/shift recomputed in-block from striped sums.
// ---------------------------------------------------------------------------

template <int K, int HOUT, bool AFF, bool XBF, bool HNBF>
__device__ void gemm_body(const void* __restrict__ Xv, const unsigned short* __restrict__ Wp,
                          const float* __restrict__ bnA, const float* __restrict__ bnB,
                          const float* __restrict__ bgA,
                          const float* __restrict__ sums, const float* __restrict__ gamma,
                          const float* __restrict__ beta,
                          float* __restrict__ Hnf, unsigned short* __restrict__ Hnb,
                          unsigned short* __restrict__ Hgb, int n, int blk)
{
    constexpr int NT = 2 * HOUT / 16, NKB = K / 32;
    constexpr int RS = K + 8;
    __shared__ unsigned short Xs[64 * RS];
    __shared__ float sSc[64], sSh[64];

    const int row0 = blk * 64;
    const int t = threadIdx.x;

    if (AFF) {               // in-block BN finalize: 1KB of reads, once per block
        if (t < 64) {
            float sum = 0.f, sq = 0.f;
#pragma unroll
            for (int s = 0; s < 8; s++) { sum += sums[s * 128 + t]; sq += sums[s * 128 + 64 + t]; }
            float m = sum / (float)NNODES;
            float var = sq / (float)NNODES - m * m;
            float sc = gamma[t] * rsqrtf(var + BN_EPS);
            sSc[t] = sc; sSh[t] = beta[t] - m * sc;
        }
        __syncthreads();
    }

    // Stage 64 x K -> bf16 LDS, 8 k-cols per step (affine+relu on the fly).
    for (int li = t; li < 64 * K / 8; li += 256) {
        int r  = li / (K / 8);
        int k8 = (li % (K / 8)) * 8;
        int rr = row0 + r;
        float v[8];
        if (XBF) {
            uint4 u = (rr < n) ? *(const uint4*)((const unsigned short*)Xv + (size_t)rr * K + k8)
                               : make_uint4(0, 0, 0, 0);
            v[0] = bf2f_lo(u.x); v[1] = bf2f_hi(u.x);
            v[2] = bf2f_lo(u.y); v[3] = bf2f_hi(u.y);
            v[4] = bf2f_lo(u.z); v[5] = bf2f_hi(u.z);
            v[6] = bf2f_lo(u.w); v[7] = bf2f_hi(u.w);
        } else {
            const float* Xf = (const float*)Xv;
            float4 a = make_float4(0.f, 0.f, 0.f, 0.f), b = a;
            if (rr < n) {
                a = *(const float4*)&Xf[(size_t)rr * K + k8];
                b = *(const float4*)&Xf[(size_t)rr * K + k8 + 4];
            }
            v[0] = a.x; v[1] = a.y; v[2] = a.z; v[3] = a.w;
            v[4] = b.x; v[5] = b.y; v[6] = b.z; v[7] = b.w;
        }
        if (AFF) {
#pragma unroll
            for (int i = 0; i < 8; i++) v[i] = fmaxf(v[i] * sSc[k8 + i] + sSh[k8 + i], 0.f);
        }
        uint4 o;
        o.x = (unsigned)f2bf(v[0]) | ((unsigned)f2bf(v[1]) << 16);
        o.y = (unsigned)f2bf(v[2]) | ((unsigned)f2bf(v[3]) << 16);
        o.z = (unsigned)f2bf(v[4]) | ((unsigned)f2bf(v[5]) << 16);
        o.w = (unsigned)f2bf(v[6]) | ((unsigned)f2bf(v[7]) << 16);
        *(uint4*)&Xs[r * RS + k8] = o;
    }
    __syncthreads();

    const int wave = t >> 6, lane = t & 63;
    const int q = lane >> 4, mrow = lane & 15;

    f32x4 acc[NT];
#pragma unroll
    for (int i = 0; i < NT; i++) acc[i] = (f32x4){0.f, 0.f, 0.f, 0.f};

    const short8* wp8 = (const short8*)Wp;
#pragma unroll
    for (int kb = 0; kb < NKB; kb++) {
        short8 a = *(const short8*)&Xs[(wave * 16 + mrow) * RS + kb * 32 + q * 8];
#pragma unroll
        for (int tt = 0; tt < NT; tt++) {
            short8 b = wp8[(kb * NT + tt) * 64 + lane];   // coalesced dwordx4
            acc[tt] = __builtin_amdgcn_mfma_f32_16x16x32_bf16(a, b, acc[tt], 0, 0, 0);
        }
    }

    // Epilogue. C/D: col = lane&15 (tile tt), row = q*4 + reg.
#pragma unroll
    for (int tt = 0; tt < NT; tt++) {
        int nglob = tt * 16 + mrow;
        bool nside = (nglob < HOUT);
        int c = nside ? nglob : (nglob - HOUT);
        float bias = 0.f;
        if (nside) {
            if (bnA) bias += bnA[c];
            if (bnB) bias += bnB[c];
        } else if (bgA) {
            bias += bgA[c];
        }
#pragma unroll
        for (int r = 0; r < 4; r++) {
            int rr = row0 + wave * 16 + q * 4 + r;
            if (rr < n) {
                float o = acc[tt][r] + bias;
                if (nside) {
                    if (HNBF) Hnb[(size_t)rr * HOUT + c] = f2bf(o);
                    else      Hnf[(size_t)rr * HOUT + c] = o;
                } else {
                    Hgb[(size_t)rr * HOUT + c] = f2bf(o);
                }
            }
        }
    }
}

// K_C: blocks [0,NCHK): bucket-partition chunk edges via LDS cursors;
//      blocks [NCHK,..): layer-0 dual GEMM (co-scheduled, independent).
__global__ __launch_bounds__(256) void part_gemm0_k(
    const int* __restrict__ rows, const int* __restrict__ cols,
    const float* __restrict__ vals, const int* __restrict__ BcntT,
    const int* __restrict__ bBase, int4* __restrict__ ebuf,
    const float* __restrict__ X, const unsigned short* __restrict__ Wp0,
    const float* __restrict__ bn0, const float* __restrict__ ab0, const float* __restrict__ bg0,
    unsigned short* __restrict__ Hn0b, unsigned short* __restrict__ Hgb, int n)
{
    if ((int)blockIdx.x < NCHK) {
        __shared__ int cur[NB];
        int t = threadIdx.x, blk = blockIdx.x;
        for (int b = t; b < NB; b += 256) cur[b] = bBase[b] + BcntT[blk * NB + b];
        __syncthreads();
        for (int i = t; i < EC; i += 256) {
            int e = blk * EC + i;
            int r = rows[e];
            int p = atomicAdd(&cur[r >> 6], 1);   // LDS atomic; ~8-edge runs/bucket
            ebuf[p] = make_int4(r, cols[e], __float_as_int(vals[e]), 0);
        }
    } else {
        gemm_body<DIN, HID, false, false, true>(X, Wp0, bn0, ab0, bg0,
            nullptr, nullptr, nullptr, nullptr, Hn0b, Hgb, n, blockIdx.x - NCHK);
    }
}

template <int K, int HOUT, bool AFF, bool XBF, bool HNBF>
__global__ __launch_bounds__(256) void gemm_k(
    const void* __restrict__ X, const unsigned short* __restrict__ Wp,
    const float* __restrict__ bnA, const float* __restrict__ bnB, const float* __restrict__ bgA,
    const float* __restrict__ sums, const float* __restrict__ gamma, const float* __restrict__ beta,
    float* __restrict__ Hnf, unsigned short* __restrict__ Hnb, unsigned short* __restrict__ Hgb, int n)
{
    gemm_body<K, HOUT, AFF, XBF, HNBF>(X, Wp, bnA, bnB, bgA, sums, gamma, beta,
                                       Hnf, Hnb, Hgb, n, blockIdx.x);
}

// ---------------------------------------------------------------------------
// Bucket SpMM: block = 64-row bucket; LDS fp32 accumulator; edges straight
// from ebuf (no row-sort, no CSR). S[row] = Hn[row] + sum val*Hg[col].
// SBF: Hn/S bf16. MARKED: only rows in idx. STATS: BN sums via 8-stripe atomics.
// ---------------------------------------------------------------------------

template <int HH, bool STATS, bool SBF, bool MARKED>
__global__ __launch_bounds__(256) void spmmb_k(
    const int4* __restrict__ ebuf, const int* __restrict__ bBase,
    const unsigned short* __restrict__ Hgb, const void* __restrict__ Hn,
    void* __restrict__ S, float* __restrict__ stats, const int* __restrict__ mark)
{
    constexpr int L = HH / 4;          // lanes per gather group (16 / 8)
    constexpr int G = 256 / L;         // groups per block
    __shared__ float acc[64 * HH];
    __shared__ int mk[64];
    const int b = blockIdx.x, t = threadIdx.x;
    const int r0 = b << 6;

    for (int i = t; i < 64 * HH; i += 256) acc[i] = 0.f;
    if (MARKED && t < 64) mk[t] = (r0 + t < NNODES) ? mark[r0 + t] : 0;
    __syncthreads();

    const int g = t / L, lane = t % L, c0 = lane * 4;
    const int e0 = bBase[b], e1 = bBase[b + 1];
    for (int e = e0 + g; e < e1; e += G) {
        int4 v = ebuf[e];                       // group-broadcast load
        int rl = v.x & 63;
        if (MARKED && !mk[rl]) continue;        // group-uniform branch
        float w = __int_as_float(v.z);
        uint2 h = *(const uint2*)&Hgb[(size_t)v.y * HH + c0];  // 128B/group coalesced
        float* a = &acc[rl * HH + c0];
        atomicAdd(a + 0, w * bf2f_lo(h.x));     // ds_add_f32, 2-way alias = free
        atomicAdd(a + 1, w * bf2f_hi(h.x));
        atomicAdd(a + 2, w * bf2f_lo(h.y));
        atomicAdd(a + 3, w * bf2f_hi(h.y));
    }
    __syncthreads();

    // Epilogue: S = Hn + acc (coalesced), per-column stats partials.
    constexpr int CG  = HH / 4;        // col-groups per row
    constexpr int RPP = 256 / CG;      // rows per pass
    const int cg = t % CG, rl0 = t / CG, cc0 = cg * 4;
    float4 ps = make_float4(0.f, 0.f, 0.f, 0.f);
    float4 pq = make_float4(0.f, 0.f, 0.f, 0.f);
    for (int pass = 0; pass < 64 / RPP; pass++) {
        int rl = pass * RPP + rl0;
        int rr = r0 + rl;
        if (rr >= NNODES) break;
        if (MARKED && !mk[rl]) continue;
        const float* a = &acc[rl * HH + cc0];
        float4 v;
        if (SBF) {
            uint2 h = *(const uint2*)((const unsigned short*)Hn + (size_t)rr * HH + cc0);
            v = make_float4(a[0] + bf2f_lo(h.x), a[1] + bf2f_hi(h.x),
                            a[2] + bf2f_lo(h.y), a[3] + bf2f_hi(h.y));
        } else {
            float4 h = *(const float4*)((const float*)Hn + (size_t)rr * HH + cc0);
            v = make_float4(a[0] + h.x, a[1] + h.y, a[2] + h.z, a[3] + h.w);
        }
        if (SBF) {
            uint2 o;
            o.x = (unsigned)f2bf(v.x) | ((unsigned)f2bf(v.y) << 16);
            o.y = (unsigned)f2bf(v.z) | ((unsigned)f2bf(v.w) << 16);
            *(uint2*)((unsigned short*)S + (size_t)rr * HH + cc0) = o;
        } else {
            *(float4*)((float*)S + (size_t)rr * HH + cc0) = v;
        }
        if (STATS) {
            ps.x += v.x; ps.y += v.y; ps.z += v.z; ps.w += v.w;
            pq.x += v.x * v.x; pq.y += v.y * v.y; pq.z += v.z * v.z; pq.w += v.w * v.w;
        }
    }

    if constexpr (STATS) {
        __syncthreads();                // acc reusable now
        *(float4*)&acc[t * 4] = ps;     // [0,1024): sums
        *(float4*)&acc[1024 + t * 4] = pq;
        __syncthreads();
        if (t < 64) {                   // col c = t
            float s = 0.f, q = 0.f;
            for (int rp = 0; rp < RPP; rp++) {
                int tt = rp * CG + (t >> 2);
                s += acc[tt * 4 + (t & 3)];
                q += acc[1024 + tt * 4 + (t & 3)];
            }
            int stripe = b & 7;
            atomicAdd(&stats[stripe * 128 + t], s);
            atomicAdd(&stats[stripe * 128 + 64 + t], q);
        }
    }
}

__global__ void gather_k(const float* __restrict__ S, const int* __restrict__ idx,
                         float* __restrict__ out, int total4) {
    int j = blockIdx.x * 256 + threadIdx.x;
    if (j < total4) {
        int r = j / (EMB / 4), c4 = (j % (EMB / 4)) * 4;
        *(float4*)&out[(size_t)j * 4] = *(const float4*)&S[(size_t)idx[r] * EMB + c4];
    }
}

// ---------------------------------------------------------------------------

extern "C" void kernel_launch(void* const* d_in, const int* in_sizes, int n_in,
                              void* d_out, int out_size, void* d_ws, size_t ws_size,
                              hipStream_t stream) {
    const float* features = (const float*)d_in[0];
    const int*   rows     = (const int*)d_in[1];
    const int*   cols     = (const int*)d_in[2];
    const float* vals     = (const float*)d_in[3];
    const int*   idx      = (const int*)d_in[4];
    const float* Wn0 = (const float*)d_in[5];
    const float* bn0 = (const float*)d_in[6];
    const float* Wg0 = (const float*)d_in[7];
    const float* bg0 = (const float*)d_in[8];
    const float* ab0 = (const float*)d_in[9];
    const float* g0  = (const float*)d_in[10];
    const float* b0  = (const float*)d_in[11];
    const float* Wn1 = (const float*)d_in[12];
    const float* Wg1 = (const float*)d_in[13];
    const float* ab1 = (const float*)d_in[14];
    const float* g1  = (const float*)d_in[15];
    const float* b1  = (const float*)d_in[16];
    const float* WnL = (const float*)d_in[17];
    const float* WgL = (const float*)d_in[18];
    const float* abL = (const float*)d_in[19];
    float* out = (float*)d_out;

    // Workspace layout (~70 MB), 16B-aligned sub-buffers.
    float*          HnLf = (float*)d_ws;                        // N x EMB fp32 (HnL/SL)
    unsigned short* nA   = (unsigned short*)(HnLf + (size_t)NNODES * EMB); // Hn0/S0 bf16
    unsigned short* nB   = nA + (size_t)NNODES * HID;           // Hn1/S1 bf16
    unsigned short* Hgb  = nB + (size_t)NNODES * HID;           // Hg (all layers) bf16
    int4*  ebuf  = (int4*)(Hgb + (size_t)NNODES * HID);         // E (bucket-partitioned)
    int*   Bcnt4 = (int*)(ebuf + NEDGES);                       // SUBC x NB
    int*   BcntT = Bcnt4 + SUBC * NB;                           // NCHK x NB
    int*   bTot  = BcntT + NCHK * NB;                           // NB (pad 1568)
    int*   bBase = bTot + 1568;                                 // NB+1 (pad 1568)
    unsigned short* Wp0 = (unsigned short*)(bBase + 1568);      // 16384
    unsigned short* Wp1 = Wp0 + 16384;                          // 8192
    unsigned short* WpL = Wp1 + 8192;                           // 4096
    // ---- single zeroed region: stats | mark ----
    float* stats = (float*)(WpL + 4096);                        // 2304
    int*   mark  = (int*)(stats + 2304);                        // N
    float* sums0 = stats;
    float* sums1 = stats + 1024;
    size_t zbytes = 2304 * 4 + (size_t)NNODES * 4;

    hipMemsetAsync(stats, 0, zbytes, stream);

    const int GBm = (NNODES + 63) / 64;     // 1563
    const int MB  = (NIDX + 255) / 256;     // 196

    packall_k<<<112, 256, 0, stream>>>(Wn0, Wg0, Wn1, Wg1, WnL, WgL, Wp0, Wp1, WpL);

    // Bucket partition (atomic-free) -----------------------------------------
    bhist_k<<<SUBC + MB, 256, 0, stream>>>(rows, Bcnt4, idx, mark);
    bprefix_k<<<7, 256, 0, stream>>>(Bcnt4, BcntT, bTot);
    bscan_k<<<1, 256, 0, stream>>>(bTot, bBase);
    part_gemm0_k<<<NCHK + GBm, 256, 0, stream>>>(rows, cols, vals, BcntT, bBase, ebuf,
                                                 features, Wp0, bn0, ab0, bg0,
                                                 nA, Hgb, NNODES);

    // Layer 0 aggregate: S0 = Hn0 + A@Hg0 (bucket-LDS accumulate, stats fp32)
    spmmb_k<HID, true, true, false><<<NB, 256, 0, stream>>>(ebuf, bBase, Hgb, nA, nA, sums0, nullptr);

    // Layer 1: BN finalize folded into gemm; S1 = Hn1 + ab1 + A@Hg1
    gemm_k<HID, HID, true, true, true><<<GBm, 256, 0, stream>>>(
        nA, Wp1, ab1, nullptr, nullptr, sums0, g0, b0, nullptr, nB, Hgb, NNODES);
    spmmb_k<HID, true, true, false><<<NB, 256, 0, stream>>>(ebuf, bBase, Hgb, nB, nB, sums1, nullptr);

    // Last layer: HnL fp32; aggregate only rows referenced by idx.
    gemm_k<HID, EMB, true, true, false><<<GBm, 256, 0, stream>>>(
        nB, WpL, abL, nullptr, nullptr, sums1, g1, b1, HnLf, nullptr, Hgb, NNODES);
    spmmb_k<EMB, false, false, true><<<NB, 256, 0, stream>>>(ebuf, bBase, Hgb, HnLf, HnLf, nullptr, mark);

    gather_k<<<(NIDX * EMB / 4 + 255) / 256, 256, 0, stream>>>(HnLf, idx, out, NIDX * EMB / 4);
}

// Round 10
// 302.961 us; speedup vs baseline: 2.9835x; 2.9835x over previous
//
#include <hip/hip_runtime.h>

// Problem constants (fixed by the reference).
#define NNODES 100000
#define NEDGES 800000
#define DIN    128
#define HID    64
#define EMB    32
#define NIDX   50000
#define BN_EPS 1e-5f

#define NCHK 64                   // partition chunks (~8-edge bucket runs)
#define EC   (NEDGES / NCHK)      // 12500 edges per chunk
#define SUBC 256                  // histogram sub-chunks (parallelism)
#define ECS  (NEDGES / SUBC)      // 3125 edges per sub-chunk
#define NB   ((NNODES + 63) / 64) // 1563 row-buckets of 64 rows

typedef __attribute__((ext_vector_type(8))) short short8;   // 8 bf16 = 4 VGPR
typedef __attribute__((ext_vector_type(4))) float f32x4;    // MFMA C/D

__device__ inline unsigned short f2bf(float f) {            // RNE, matches HW
    unsigned u = __float_as_uint(f);
    unsigned r = u + 0x7FFFu + ((u >> 16) & 1u);
    return (unsigned short)(r >> 16);
}
__device__ inline float bf2f_lo(unsigned u) { return __uint_as_float(u << 16); }
__device__ inline float bf2f_hi(unsigned u) { return __uint_as_float(u & 0xffff0000u); }

// ---------------------------------------------------------------------------
// W pre-pack (all three layers): fp32 [Wn|Wg] -> bf16 B-fragment-major.
// ---------------------------------------------------------------------------

__device__ inline void pack_seg(const float* __restrict__ Wn, const float* __restrict__ Wg,
                                unsigned short* __restrict__ Wp, int HOUT, int l2nt, int f) {
    int j = f & 7, lane = (f >> 3) & 63, g = f >> 9;
    int tt = g & ((1 << l2nt) - 1), kb = g >> l2nt;
    int k = kb * 32 + ((lane >> 4) * 8) + j;
    int nn = tt * 16 + (lane & 15);
    float v = (nn < HOUT) ? Wn[k * HOUT + nn] : Wg[k * HOUT + (nn - HOUT)];
    Wp[f] = f2bf(v);
}

__global__ void packall_k(const float* Wn0, const float* Wg0, const float* Wn1,
                          const float* Wg1, const float* WnL, const float* WgL,
                          unsigned short* Wp0, unsigned short* Wp1, unsigned short* WpL) {
    int f = blockIdx.x * 256 + threadIdx.x;
    if (f < 16384)      pack_seg(Wn0, Wg0, Wp0, 64, 3, f);           // 128x128
    else if (f < 24576) pack_seg(Wn1, Wg1, Wp1, 64, 3, f - 16384);   // 64x128
    else if (f < 28672) pack_seg(WnL, WgL, WpL, 32, 2, f - 24576);   // 64x64
}

// ---------------------------------------------------------------------------
// Bucket partition (LDS atomics only in build; NONE on SpMM hot path --
// round 9 measured per-edge LDS atomic RMW at ~300us/layer: never again).
// ---------------------------------------------------------------------------

__global__ __launch_bounds__(256) void bhist_k(const int* __restrict__ rows,
                                               int* __restrict__ Bcnt4,
                                               const int* __restrict__ idx,
                                               int* __restrict__ mark) {
    if ((int)blockIdx.x >= SUBC) {
        int j = ((int)blockIdx.x - SUBC) * 256 + threadIdx.x;
        if (j < NIDX) mark[idx[j]] = 1;
        return;
    }
    __shared__ int hist[NB];
    int t = threadIdx.x, blk = blockIdx.x;
    for (int b = t; b < NB; b += 256) hist[b] = 0;
    __syncthreads();
    for (int i = t; i < ECS; i += 256)
        atomicAdd(&hist[rows[blk * ECS + i] >> 6], 1);
    __syncthreads();
    for (int b = t; b < NB; b += 256) Bcnt4[blk * NB + b] = hist[b];
}

__global__ void bprefix_k(const int* __restrict__ Bcnt4, int* __restrict__ BcntT,
                          int* __restrict__ bTot) {
    int b = blockIdx.x * 256 + threadIdx.x;
    if (b >= NB) return;
    int run = 0;
    for (int sub = 0; sub < SUBC; sub++) {
        if ((sub & 3) == 0) BcntT[(sub >> 2) * NB + b] = run;  // chunk = sub/4
        run += Bcnt4[sub * NB + b];                            // coalesced
    }
    bTot[b] = run;
}

__global__ void bscan_k(const int* __restrict__ bTot, int* __restrict__ bBase) {
    __shared__ int s[256];
    int t = threadIdx.x;
    int v[7], loc = 0;
#pragma unroll
    for (int i = 0; i < 7; i++) {
        int ix = t * 7 + i;
        v[i] = loc;
        loc += (ix < NB) ? bTot[ix] : 0;
    }
    s[t] = loc;
    __syncthreads();
    for (int off = 1; off < 256; off <<= 1) {
        int a = (t >= off) ? s[t - off] : 0;
        __syncthreads();
        s[t] += a;
        __syncthreads();
    }
    int base = s[t] - loc;
#pragma unroll
    for (int i = 0; i < 7; i++) {
        int ix = t * 7 + i;
        if (ix < NB) bBase[ix] = base + v[i];
    }
    if (t == 255) bBase[NB] = NEDGES;
}

// bfinal: one block per bucket (64 rows, ~512 edges): LDS 64-bin hist + scan
//         -> rowptr; scatter {col,val} into final row-sorted cs.
__global__ __launch_bounds__(256) void bfinal_k(const int4* __restrict__ ebuf,
                                                const int* __restrict__ bBase,
                                                int* __restrict__ rowptr,
                                                int2* __restrict__ cs) {
    __shared__ int hist[64], sc[64], cur[64];
    int b = blockIdx.x, t = threadIdx.x;
    int e0 = bBase[b], e1 = bBase[b + 1];
    int r0 = b << 6;
    if (t < 64) hist[t] = 0;
    __syncthreads();
    for (int i = e0 + t; i < e1; i += 256)
        atomicAdd(&hist[ebuf[i].x & 63], 1);
    __syncthreads();
    if (t == 0) {
        int run = e0;
        for (int j = 0; j < 64; j++) { sc[j] = run; run += hist[j]; }
    }
    __syncthreads();
    if (t < 64) {
        cur[t] = sc[t];
        int r = r0 + t;
        if (r < NNODES) rowptr[r] = sc[t];
    }
    if (b == NB - 1 && t == 0) rowptr[NNODES] = NEDGES;
    __syncthreads();
    for (int i = e0 + t; i < e1; i += 256) {
        int4 v = ebuf[i];
        int p = atomicAdd(&cur[v.x & 63], 1);
        cs[p] = make_int2(v.y, v.z);
    }
}

// ---------------------------------------------------------------------------
// MFMA dual-GEMM body. [Hn | Hg] = act(X) @ [Wn | Wg] (+ per-col biases);
// Hg always bf16 out; Hn bf16 (HNBF) or fp32. X fp32 or bf16 (XBF).
// AFF: BN scale/shift recomputed in-block from striped sums.
// ---------------------------------------------------------------------------

template <int K, int HOUT, bool AFF, bool XBF, bool HNBF>
__device__ void gemm_body(const void* __restrict__ Xv, const unsigned short* __restrict__ Wp,
                          const float* __restrict__ bnA, const float* __restrict__ bnB,
                          const float* __restrict__ bgA,
                          const float* __restrict__ sums, const float* __restrict__ gamma,
                          const float* __restrict__ beta,
                          float* __restrict__ Hnf, unsigned short* __restrict__ Hnb,
                          unsigned short* __restrict__ Hgb, int n, int blk)
{
    constexpr int NT = 2 * HOUT / 16, NKB = K / 32;
    constexpr int RS = K + 8;
    __shared__ unsigned short Xs[64 * RS];
    __shared__ float sSc[64], sSh[64];

    const int row0 = blk * 64;
    const int t = threadIdx.x;

    if (AFF) {               // in-block BN finalize: 1KB of reads, once per block
        if (t < 64) {
            float sum = 0.f, sq = 0.f;
#pragma unroll
            for (int s = 0; s < 8; s++) { sum += sums[s * 128 + t]; sq += sums[s * 128 + 64 + t]; }
            float m = sum / (float)NNODES;
            float var = sq / (float)NNODES - m * m;
            float sc = gamma[t] * rsqrtf(var + BN_EPS);
            sSc[t] = sc; sSh[t] = beta[t] - m * sc;
        }
        __syncthreads();
    }

    // Stage 64 x K -> bf16 LDS, 8 k-cols per step (affine+relu on the fly).
    for (int li = t; li < 64 * K / 8; li += 256) {
        int r  = li / (K / 8);
        int k8 = (li % (K / 8)) * 8;
        int rr = row0 + r;
        float v[8];
        if (XBF) {
            uint4 u = (rr < n) ? *(const uint4*)((const unsigned short*)Xv + (size_t)rr * K + k8)
                               : make_uint4(0, 0, 0, 0);
            v[0] = bf2f_lo(u.x); v[1] = bf2f_hi(u.x);
            v[2] = bf2f_lo(u.y); v[3] = bf2f_hi(u.y);
            v[4] = bf2f_lo(u.z); v[5] = bf2f_hi(u.z);
            v[6] = bf2f_lo(u.w); v[7] = bf2f_hi(u.w);
        } else {
            const float* Xf = (const float*)Xv;
            float4 a = make_float4(0.f, 0.f, 0.f, 0.f), b = a;
            if (rr < n) {
                a = *(const float4*)&Xf[(size_t)rr * K + k8];
                b = *(const float4*)&Xf[(size_t)rr * K + k8 + 4];
            }
            v[0] = a.x; v[1] = a.y; v[2] = a.z; v[3] = a.w;
            v[4] = b.x; v[5] = b.y; v[6] = b.z; v[7] = b.w;
        }
        if (AFF) {
#pragma unroll
            for (int i = 0; i < 8; i++) v[i] = fmaxf(v[i] * sSc[k8 + i] + sSh[k8 + i], 0.f);
        }
        uint4 o;
        o.x = (unsigned)f2bf(v[0]) | ((unsigned)f2bf(v[1]) << 16);
        o.y = (unsigned)f2bf(v[2]) | ((unsigned)f2bf(v[3]) << 16);
        o.z = (unsigned)f2bf(v[4]) | ((unsigned)f2bf(v[5]) << 16);
        o.w = (unsigned)f2bf(v[6]) | ((unsigned)f2bf(v[7]) << 16);
        *(uint4*)&Xs[r * RS + k8] = o;
    }
    __syncthreads();

    const int wave = t >> 6, lane = t & 63;
    const int q = lane >> 4, mrow = lane & 15;

    f32x4 acc[NT];
#pragma unroll
    for (int i = 0; i < NT; i++) acc[i] = (f32x4){0.f, 0.f, 0.f, 0.f};

    const short8* wp8 = (const short8*)Wp;
#pragma unroll
    for (int kb = 0; kb < NKB; kb++) {
        short8 a = *(const short8*)&Xs[(wave * 16 + mrow) * RS + kb * 32 + q * 8];
#pragma unroll
        for (int tt = 0; tt < NT; tt++) {
            short8 b = wp8[(kb * NT + tt) * 64 + lane];   // coalesced dwordx4
            acc[tt] = __builtin_amdgcn_mfma_f32_16x16x32_bf16(a, b, acc[tt], 0, 0, 0);
        }
    }

    // Epilogue. C/D: col = lane&15 (tile tt), row = q*4 + reg.
#pragma unroll
    for (int tt = 0; tt < NT; tt++) {
        int nglob = tt * 16 + mrow;
        bool nside = (nglob < HOUT);
        int c = nside ? nglob : (nglob - HOUT);
        float bias = 0.f;
        if (nside) {
            if (bnA) bias += bnA[c];
            if (bnB) bias += bnB[c];
        } else if (bgA) {
            bias += bgA[c];
        }
#pragma unroll
        for (int r = 0; r < 4; r++) {
            int rr = row0 + wave * 16 + q * 4 + r;
            if (rr < n) {
                float o = acc[tt][r] + bias;
                if (nside) {
                    if (HNBF) Hnb[(size_t)rr * HOUT + c] = f2bf(o);
                    else      Hnf[(size_t)rr * HOUT + c] = o;
                } else {
                    Hgb[(size_t)rr * HOUT + c] = f2bf(o);
                }
            }
        }
    }
}

// K_C: blocks [0,NCHK): bucket-partition chunk edges via LDS cursors;
//      blocks [NCHK,..): layer-0 dual GEMM (co-scheduled, independent).
__global__ __launch_bounds__(256) void part_gemm0_k(
    const int* __restrict__ rows, const int* __restrict__ cols,
    const float* __restrict__ vals, const int* __restrict__ BcntT,
    const int* __restrict__ bBase, int4* __restrict__ ebuf,
    const float* __restrict__ X, const unsigned short* __restrict__ Wp0,
    const float* __restrict__ bn0, const float* __restrict__ ab0, const float* __restrict__ bg0,
    unsigned short* __restrict__ Hn0b, unsigned short* __restrict__ Hgb, int n)
{
    if ((int)blockIdx.x < NCHK) {
        __shared__ int cur[NB];
        int t = threadIdx.x, blk = blockIdx.x;
        for (int b = t; b < NB; b += 256) cur[b] = bBase[b] + BcntT[blk * NB + b];
        __syncthreads();
        for (int i = t; i < EC; i += 256) {
            int e = blk * EC + i;
            int r = rows[e];
            int p = atomicAdd(&cur[r >> 6], 1);   // LDS atomic; ~8-edge runs/bucket
            ebuf[p] = make_int4(r, cols[e], __float_as_int(vals[e]), 0);
        }
    } else {
        gemm_body<DIN, HID, false, false, true>(X, Wp0, bn0, ab0, bg0,
            nullptr, nullptr, nullptr, nullptr, Hn0b, Hgb, n, blockIdx.x - NCHK);
    }
}

template <int K, int HOUT, bool AFF, bool XBF, bool HNBF>
__global__ __launch_bounds__(256) void gemm_k(
    const void* __restrict__ X, const unsigned short* __restrict__ Wp,
    const float* __restrict__ bnA, const float* __restrict__ bnB, const float* __restrict__ bgA,
    const float* __restrict__ sums, const float* __restrict__ gamma, const float* __restrict__ beta,
    float* __restrict__ Hnf, unsigned short* __restrict__ Hnb, unsigned short* __restrict__ Hgb, int n)
{
    gemm_body<K, HOUT, AFF, XBF, HNBF>(X, Wp, bnA, bnB, bgA, sums, gamma, beta,
                                       Hnf, Hnb, Hgb, n, blockIdx.x);
}

// ---------------------------------------------------------------------------
// SpMM (row-sorted CSR gather): S[row] = Hn[row] + sum val*Hg[col], Hg bf16,
// register accumulation (NO atomics on the edge path).
// SBF: Hn/S bf16. MARKED: skip rows not in idx. STATS: striped BN sums.
// ---------------------------------------------------------------------------

template <int HH, bool STATS, bool SBF, bool MARKED>
__global__ __launch_bounds__(256) void spmm_k(
    const int* __restrict__ rowptr, const int2* __restrict__ cs,
    const unsigned short* __restrict__ Hgb, void* __restrict__ Sv,
    float* __restrict__ stats, const int* __restrict__ mark, int n)
{
    constexpr int L  = HH / 4;
    constexpr int GP = 256 / L;
    const int lane = threadIdx.x % L;
    const int g = threadIdx.x / L;
    const int gid = blockIdx.x * GP + g;
    const int ngroups = gridDim.x * GP;
    const int c0 = lane * 4;

    float4 sum = make_float4(0.f, 0.f, 0.f, 0.f);
    float4 sq  = make_float4(0.f, 0.f, 0.f, 0.f);
    for (int row = gid; row < n; row += ngroups) {
        if (MARKED && !mark[row]) continue;
        int e0 = rowptr[row], e1 = rowptr[row + 1];
        float4 a0, a1 = make_float4(0.f, 0.f, 0.f, 0.f);
        if (SBF) {
            uint2 h = *(const uint2*)((const unsigned short*)Sv + (size_t)row * HH + c0);
            a0 = make_float4(bf2f_lo(h.x), bf2f_hi(h.x), bf2f_lo(h.y), bf2f_hi(h.y));
        } else {
            a0 = *(const float4*)((const float*)Sv + (size_t)row * HH + c0);
        }
        int e = e0;
        for (; e + 1 < e1; e += 2) {
            int2 p0 = cs[e], p1 = cs[e + 1];
            float v0 = __int_as_float(p0.y), v1 = __int_as_float(p1.y);
            uint2 h0 = *(const uint2*)&Hgb[(size_t)p0.x * HH + c0];
            uint2 h1 = *(const uint2*)&Hgb[(size_t)p1.x * HH + c0];
            a0.x += v0 * bf2f_lo(h0.x); a0.y += v0 * bf2f_hi(h0.x);
            a0.z += v0 * bf2f_lo(h0.y); a0.w += v0 * bf2f_hi(h0.y);
            a1.x += v1 * bf2f_lo(h1.x); a1.y += v1 * bf2f_hi(h1.x);
            a1.z += v1 * bf2f_lo(h1.y); a1.w += v1 * bf2f_hi(h1.y);
        }
        if (e < e1) {
            int2 p = cs[e];
            float v = __int_as_float(p.y);
            uint2 h = *(const uint2*)&Hgb[(size_t)p.x * HH + c0];
            a0.x += v * bf2f_lo(h.x); a0.y += v * bf2f_hi(h.x);
            a0.z += v * bf2f_lo(h.y); a0.w += v * bf2f_hi(h.y);
        }
        float4 acc = make_float4(a0.x + a1.x, a0.y + a1.y, a0.z + a1.z, a0.w + a1.w);
        if (SBF) {
            uint2 o;
            o.x = (unsigned)f2bf(acc.x) | ((unsigned)f2bf(acc.y) << 16);
            o.y = (unsigned)f2bf(acc.z) | ((unsigned)f2bf(acc.w) << 16);
            *(uint2*)((unsigned short*)Sv + (size_t)row * HH + c0) = o;
        } else {
            *(float4*)((float*)Sv + (size_t)row * HH + c0) = acc;
        }
        if (STATS) {
            sum.x += acc.x; sum.y += acc.y; sum.z += acc.z; sum.w += acc.w;
            sq.x += acc.x * acc.x; sq.y += acc.y * acc.y;
            sq.z += acc.z * acc.z; sq.w += acc.w * acc.w;
        }
    }

    if constexpr (STATS) {
        __shared__ float rs[GP][HH];
        __shared__ float rq[GP][HH];
        *(float4*)&rs[g][c0] = sum;
        *(float4*)&rq[g][c0] = sq;
        __syncthreads();
        if (threadIdx.x < HH) {
            float a = 0.f, b = 0.f;
            for (int w = 0; w < GP; w++) { a += rs[w][threadIdx.x]; b += rq[w][threadIdx.x]; }
            int stripe = blockIdx.x & 7;
            atomicAdd(&stats[stripe * 128 + threadIdx.x], a);
            atomicAdd(&stats[stripe * 128 + HH + threadIdx.x], b);
        }
    }
}

__global__ void gather_k(const float* __restrict__ S, const int* __restrict__ idx,
                         float* __restrict__ out, int total4) {
    int j = blockIdx.x * 256 + threadIdx.x;
    if (j < total4) {
        int r = j / (EMB / 4), c4 = (j % (EMB / 4)) * 4;
        *(float4*)&out[(size_t)j * 4] = *(const float4*)&S[(size_t)idx[r] * EMB + c4];
    }
}

// ---------------------------------------------------------------------------

extern "C" void kernel_launch(void* const* d_in, const int* in_sizes, int n_in,
                              void* d_out, int out_size, void* d_ws, size_t ws_size,
                              hipStream_t stream) {
    const float* features = (const float*)d_in[0];
    const int*   rows     = (const int*)d_in[1];
    const int*   cols     = (const int*)d_in[2];
    const float* vals     = (const float*)d_in[3];
    const int*   idx      = (const int*)d_in[4];
    const float* Wn0 = (const float*)d_in[5];
    const float* bn0 = (const float*)d_in[6];
    const float* Wg0 = (const float*)d_in[7];
    const float* bg0 = (const float*)d_in[8];
    const float* ab0 = (const float*)d_in[9];
    const float* g0  = (const float*)d_in[10];
    const float* b0  = (const float*)d_in[11];
    const float* Wn1 = (const float*)d_in[12];
    const float* Wg1 = (const float*)d_in[13];
    const float* ab1 = (const float*)d_in[14];
    const float* g1  = (const float*)d_in[15];
    const float* b1  = (const float*)d_in[16];
    const float* WnL = (const float*)d_in[17];
    const float* WgL = (const float*)d_in[18];
    const float* abL = (const float*)d_in[19];
    float* out = (float*)d_out;

    // Workspace layout (~77 MB), 16B-aligned sub-buffers.
    float*          HnLf = (float*)d_ws;                        // N x EMB fp32 (HnL/SL)
    unsigned short* nA   = (unsigned short*)(HnLf + (size_t)NNODES * EMB); // Hn0/S0 bf16
    unsigned short* nB   = nA + (size_t)NNODES * HID;           // Hn1/S1 bf16
    unsigned short* Hgb  = nB + (size_t)NNODES * HID;           // Hg (all layers) bf16
    int4*  ebuf  = (int4*)(Hgb + (size_t)NNODES * HID);         // E (bucket-partitioned)
    int2*  cs    = (int2*)(ebuf + NEDGES);                      // E (row-sorted payload)
    int*   rowptr = (int*)(cs + NEDGES);                        // N+4
    int*   Bcnt4 = rowptr + (NNODES + 4);                       // SUBC x NB
    int*   BcntT = Bcnt4 + SUBC * NB;                           // NCHK x NB
    int*   bTot  = BcntT + NCHK * NB;                           // NB (pad 1568)
    int*   bBase = bTot + 1568;                                 // NB+1 (pad 1568)
    unsigned short* Wp0 = (unsigned short*)(bBase + 1568);      // 16384
    unsigned short* Wp1 = Wp0 + 16384;                          // 8192
    unsigned short* WpL = Wp1 + 8192;                           // 4096
    // ---- single zeroed region: stats | mark ----
    float* stats = (float*)(WpL + 4096);                        // 2304
    int*   mark  = (int*)(stats + 2304);                        // N
    float* sums0 = stats;
    float* sums1 = stats + 1024;
    size_t zbytes = 2304 * 4 + (size_t)NNODES * 4;

    hipMemsetAsync(stats, 0, zbytes, stream);

    const int GBm = (NNODES + 63) / 64;     // 1563
    const int MB  = (NIDX + 255) / 256;     // 196

    packall_k<<<112, 256, 0, stream>>>(Wn0, Wg0, Wn1, Wg1, WnL, WgL, Wp0, Wp1, WpL);

    // Bucket partition + row sort (no global atomics) -------------------------
    bhist_k<<<SUBC + MB, 256, 0, stream>>>(rows, Bcnt4, idx, mark);
    bprefix_k<<<7, 256, 0, stream>>>(Bcnt4, BcntT, bTot);
    bscan_k<<<1, 256, 0, stream>>>(bTot, bBase);
    part_gemm0_k<<<NCHK + GBm, 256, 0, stream>>>(rows, cols, vals, BcntT, bBase, ebuf,
                                                 features, Wp0, bn0, ab0, bg0,
                                                 nA, Hgb, NNODES);
    bfinal_k<<<NB, 256, 0, stream>>>(ebuf, bBase, rowptr, cs);

    // Layer 0 aggregate: S0 = Hn0 + A@Hg0 (bf16 in/out, stats fp32)
    spmm_k<HID, true, true, false><<<1600, 256, 0, stream>>>(rowptr, cs, Hgb, nA, sums0, nullptr, NNODES);

    // Layer 1: BN finalize folded into gemm; S1 = Hn1 + ab1 + A@Hg1
    gemm_k<HID, HID, true, true, true><<<GBm, 256, 0, stream>>>(
        nA, Wp1, ab1, nullptr, nullptr, sums0, g0, b0, nullptr, nB, Hgb, NNODES);
    spmm_k<HID, true, true, false><<<1600, 256, 0, stream>>>(rowptr, cs, Hgb, nB, sums1, nullptr, NNODES);

    // Last layer: HnL fp32; aggregate only rows referenced by idx.
    gemm_k<HID, EMB, true, true, false><<<GBm, 256, 0, stream>>>(
        nB, WpL, abL, nullptr, nullptr, sums1, g1, b1, HnLf, nullptr, Hgb, NNODES);
    spmm_k<EMB, false, false, true><<<1600, 256, 0, stream>>>(rowptr, cs, Hgb, HnLf, nullptr, mark, NNODES);

    gather_k<<<(NIDX * EMB / 4 + 255) / 256, 256, 0, stream>>>(HnLf, idx, out, NIDX * EMB / 4);
}

// Round 11
// 282.563 us; speedup vs baseline: 3.1988x; 1.0722x over previous
//
#include <hip/hip_runtime.h>

// Problem constants (fixed by the reference).
#define NNODES 100000
#define NEDGES 800000
#define DIN    128
#define HID    64
#define EMB    32
#define NIDX   50000
#define BN_EPS 1e-5f

#define NCHK 256                  // partition chunks (parallelism >> write-amp)
#define EC   (NEDGES / NCHK)      // 3125 edges per chunk
#define SUBC 256                  // histogram sub-chunks (== NCHK)
#define ECS  (NEDGES / SUBC)      // 3125
#define NB   ((NNODES + 63) / 64) // 1563 row-buckets of 64 rows

typedef __attribute__((ext_vector_type(8))) short short8;   // 8 bf16 = 4 VGPR
typedef __attribute__((ext_vector_type(4))) float f32x4;    // MFMA C/D

__device__ inline unsigned short f2bf(float f) {            // RNE, matches HW
    unsigned u = __float_as_uint(f);
    unsigned r = u + 0x7FFFu + ((u >> 16) & 1u);
    return (unsigned short)(r >> 16);
}
__device__ inline float bf2f_lo(unsigned u) { return __uint_as_float(u << 16); }
__device__ inline float bf2f_hi(unsigned u) { return __uint_as_float(u & 0xffff0000u); }

// ---------------------------------------------------------------------------
// W pre-pack: fp32 [Wn|Wg] -> bf16 B-fragment-major (GEMM B-loads coalesced).
// ---------------------------------------------------------------------------

__device__ inline void pack_seg(const float* __restrict__ Wn, const float* __restrict__ Wg,
                                unsigned short* __restrict__ Wp, int HOUT, int l2nt, int f) {
    int j = f & 7, lane = (f >> 3) & 63, g = f >> 9;
    int tt = g & ((1 << l2nt) - 1), kb = g >> l2nt;
    int k = kb * 32 + ((lane >> 4) * 8) + j;
    int nn = tt * 16 + (lane & 15);
    float v = (nn < HOUT) ? Wn[k * HOUT + nn] : Wg[k * HOUT + (nn - HOUT)];
    Wp[f] = f2bf(v);
}

// ---------------------------------------------------------------------------
// K1: blocks [0,SUBC): bucket histogram (bucket = row>>6) -> Bcnt4[sub][b]
//     blocks [SUBC,SUBC+MB): mark[idx[j]] = 1
//     blocks [SUBC+MB,..): W pre-pack (all 3 layers)  -- all independent.
// ---------------------------------------------------------------------------

__global__ __launch_bounds__(256) void histpack_k(
    const int* __restrict__ rows, int* __restrict__ Bcnt4,
    const int* __restrict__ idx, int* __restrict__ mark,
    const float* Wn0, const float* Wg0, const float* Wn1,
    const float* Wg1, const float* WnL, const float* WgL,
    unsigned short* Wp0, unsigned short* Wp1, unsigned short* WpL, int MB)
{
    int blk = blockIdx.x;
    if (blk >= SUBC + MB) {
        int f = (blk - SUBC - MB) * 256 + threadIdx.x;
        if (f < 16384)      pack_seg(Wn0, Wg0, Wp0, 64, 3, f);           // 128x128
        else if (f < 24576) pack_seg(Wn1, Wg1, Wp1, 64, 3, f - 16384);   // 64x128
        else if (f < 28672) pack_seg(WnL, WgL, WpL, 32, 2, f - 24576);   // 64x64
        return;
    }
    if (blk >= SUBC) {
        int j = (blk - SUBC) * 256 + threadIdx.x;
        if (j < NIDX) mark[idx[j]] = 1;
        return;
    }
    __shared__ int hist[NB];
    int t = threadIdx.x;
    for (int b = t; b < NB; b += 256) hist[b] = 0;
    __syncthreads();
    for (int i = t; i < ECS; i += 256)
        atomicAdd(&hist[rows[blk * ECS + i] >> 6], 1);
    __syncthreads();
    for (int b = t; b < NB; b += 256) Bcnt4[blk * NB + b] = hist[b];
}

__global__ void bprefix_k(const int* __restrict__ Bcnt4, int* __restrict__ BcntT,
                          int* __restrict__ bTot) {
    int b = blockIdx.x * 256 + threadIdx.x;
    if (b >= NB) return;
    int run = 0;
    for (int sub = 0; sub < SUBC; sub++) {
        BcntT[sub * NB + b] = run;       // coalesced read & write
        run += Bcnt4[sub * NB + b];
    }
    bTot[b] = run;
}

__global__ void bscan_k(const int* __restrict__ bTot, int* __restrict__ bBase) {
    __shared__ int s[256];
    int t = threadIdx.x;
    int v[7], loc = 0;
#pragma unroll
    for (int i = 0; i < 7; i++) {
        int ix = t * 7 + i;
        v[i] = loc;
        loc += (ix < NB) ? bTot[ix] : 0;
    }
    s[t] = loc;
    __syncthreads();
    for (int off = 1; off < 256; off <<= 1) {
        int a = (t >= off) ? s[t - off] : 0;
        __syncthreads();
        s[t] += a;
        __syncthreads();
    }
    int base = s[t] - loc;
#pragma unroll
    for (int i = 0; i < 7; i++) {
        int ix = t * 7 + i;
        if (ix < NB) bBase[ix] = base + v[i];
    }
    if (t == 255) bBase[NB] = NEDGES;
}

// bfinal: one block per bucket (64 rows, ~512 edges): LDS 64-bin hist + scan
//         -> rowptr; scatter {col,val} into final row-sorted cs.
// ebuf entry: x = (row&63)<<20 | col, y = val bits  (8 B/edge).
__global__ __launch_bounds__(256) void bfinal_k(const uint2* __restrict__ ebuf,
                                                const int* __restrict__ bBase,
                                                int* __restrict__ rowptr,
                                                int2* __restrict__ cs) {
    __shared__ int hist[64], sc[64], cur[64];
    int b = blockIdx.x, t = threadIdx.x;
    int e0 = bBase[b], e1 = bBase[b + 1];
    int r0 = b << 6;
    if (t < 64) hist[t] = 0;
    __syncthreads();
    for (int i = e0 + t; i < e1; i += 256)
        atomicAdd(&hist[(ebuf[i].x >> 20) & 63], 1);
    __syncthreads();
    if (t == 0) {
        int run = e0;
        for (int j = 0; j < 64; j++) { sc[j] = run; run += hist[j]; }
    }
    __syncthreads();
    if (t < 64) {
        cur[t] = sc[t];
        int r = r0 + t;
        if (r < NNODES) rowptr[r] = sc[t];
    }
    if (b == NB - 1 && t == 0) rowptr[NNODES] = NEDGES;
    __syncthreads();
    for (int i = e0 + t; i < e1; i += 256) {
        uint2 v = ebuf[i];
        int p = atomicAdd(&cur[(v.x >> 20) & 63], 1);
        cs[p] = make_int2((int)(v.x & 0xFFFFF), (int)v.y);
    }
}

// ---------------------------------------------------------------------------
// MFMA dual-GEMM body. [Hn | Hg] = act(X) @ [Wn | Wg] (+ per-col biases);
// Hg always bf16 out; Hn bf16 (HNBF) or fp32. X fp32 or bf16 (XBF).
// AFF: BN scale/shift recomputed in-block from striped sums.
// ---------------------------------------------------------------------------

template <int K, int HOUT, bool AFF, bool XBF, bool HNBF>
__device__ void gemm_body(const void* __restrict__ Xv, const unsigned short* __restrict__ Wp,
                          const float* __restrict__ bnA, const float* __restrict__ bnB,
                          const float* __restrict__ bgA,
                          const float* __restrict__ sums, const float* __restrict__ gamma,
                          const float* __restrict__ beta,
                          float* __restrict__ Hnf, unsigned short* __restrict__ Hnb,
                          unsigned short* __restrict__ Hgb, int n, int blk)
{
    constexpr int NT = 2 * HOUT / 16, NKB = K / 32;
    constexpr int RS = K + 8;
    __shared__ unsigned short Xs[64 * RS];
    __shared__ float sSc[64], sSh[64];

    const int row0 = blk * 64;
    const int t = threadIdx.x;

    if (AFF) {               // in-block BN finalize: 1KB of reads, once per block
        if (t < 64) {
            float sum = 0.f, sq = 0.f;
#pragma unroll
            for (int s = 0; s < 8; s++) { sum += sums[s * 128 + t]; sq += sums[s * 128 + 64 + t]; }
            float m = sum / (float)NNODES;
            float var = sq / (float)NNODES - m * m;
            float sc = gamma[t] * rsqrtf(var + BN_EPS);
            sSc[t] = sc; sSh[t] = beta[t] - m * sc;
        }
        __syncthreads();
    }

    // Stage 64 x K -> bf16 LDS, 8 k-cols per step (affine+relu on the fly).
    for (int li = t; li < 64 * K / 8; li += 256) {
        int r  = li / (K / 8);
        int k8 = (li % (K / 8)) * 8;
        int rr = row0 + r;
        float v[8];
        if (XBF) {
            uint4 u = (rr < n) ? *(const uint4*)((const unsigned short*)Xv + (size_t)rr * K + k8)
                               : make_uint4(0, 0, 0, 0);
            v[0] = bf2f_lo(u.x); v[1] = bf2f_hi(u.x);
            v[2] = bf2f_lo(u.y); v[3] = bf2f_hi(u.y);
            v[4] = bf2f_lo(u.z); v[5] = bf2f_hi(u.z);
            v[6] = bf2f_lo(u.w); v[7] = bf2f_hi(u.w);
        } else {
            const float* Xf = (const float*)Xv;
            float4 a = make_float4(0.f, 0.f, 0.f, 0.f), b = a;
            if (rr < n) {
                a = *(const float4*)&Xf[(size_t)rr * K + k8];
                b = *(const float4*)&Xf[(size_t)rr * K + k8 + 4];
            }
            v[0] = a.x; v[1] = a.y; v[2] = a.z; v[3] = a.w;
            v[4] = b.x; v[5] = b.y; v[6] = b.z; v[7] = b.w;
        }
        if (AFF) {
#pragma unroll
            for (int i = 0; i < 8; i++) v[i] = fmaxf(v[i] * sSc[k8 + i] + sSh[k8 + i], 0.f);
        }
        uint4 o;
        o.x = (unsigned)f2bf(v[0]) | ((unsigned)f2bf(v[1]) << 16);
        o.y = (unsigned)f2bf(v[2]) | ((unsigned)f2bf(v[3]) << 16);
        o.z = (unsigned)f2bf(v[4]) | ((unsigned)f2bf(v[5]) << 16);
        o.w = (unsigned)f2bf(v[6]) | ((unsigned)f2bf(v[7]) << 16);
        *(uint4*)&Xs[r * RS + k8] = o;
    }
    __syncthreads();

    const int wave = t >> 6, lane = t & 63;
    const int q = lane >> 4, mrow = lane & 15;

    f32x4 acc[NT];
#pragma unroll
    for (int i = 0; i < NT; i++) acc[i] = (f32x4){0.f, 0.f, 0.f, 0.f};

    const short8* wp8 = (const short8*)Wp;
#pragma unroll
    for (int kb = 0; kb < NKB; kb++) {
        short8 a = *(const short8*)&Xs[(wave * 16 + mrow) * RS + kb * 32 + q * 8];
#pragma unroll
        for (int tt = 0; tt < NT; tt++) {
            short8 b = wp8[(kb * NT + tt) * 64 + lane];   // coalesced dwordx4
            acc[tt] = __builtin_amdgcn_mfma_f32_16x16x32_bf16(a, b, acc[tt], 0, 0, 0);
        }
    }

    // Epilogue. C/D: col = lane&15 (tile tt), row = q*4 + reg.
#pragma unroll
    for (int tt = 0; tt < NT; tt++) {
        int nglob = tt * 16 + mrow;
        bool nside = (nglob < HOUT);
        int c = nside ? nglob : (nglob - HOUT);
        float bias = 0.f;
        if (nside) {
            if (bnA) bias += bnA[c];
            if (bnB) bias += bnB[c];
        } else if (bgA) {
            bias += bgA[c];
        }
#pragma unroll
        for (int r = 0; r < 4; r++) {
            int rr = row0 + wave * 16 + q * 4 + r;
            if (rr < n) {
                float o = acc[tt][r] + bias;
                if (nside) {
                    if (HNBF) Hnb[(size_t)rr * HOUT + c] = f2bf(o);
                    else      Hnf[(size_t)rr * HOUT + c] = o;
                } else {
                    Hgb[(size_t)rr * HOUT + c] = f2bf(o);
                }
            }
        }
    }
}

// K_C: blocks [0,NCHK): bucket-partition chunk edges via LDS cursors (8B
//      packed entries); blocks [NCHK,..): layer-0 dual GEMM (co-scheduled).
__global__ __launch_bounds__(256) void part_gemm0_k(
    const int* __restrict__ rows, const int* __restrict__ cols,
    const float* __restrict__ vals, const int* __restrict__ BcntT,
    const int* __restrict__ bBase, uint2* __restrict__ ebuf,
    const float* __restrict__ X, const unsigned short* __restrict__ Wp0,
    const float* __restrict__ bn0, const float* __restrict__ ab0, const float* __restrict__ bg0,
    unsigned short* __restrict__ Hn0b, unsigned short* __restrict__ Hgb, int n)
{
    if ((int)blockIdx.x < NCHK) {
        __shared__ int cur[NB];
        int t = threadIdx.x, blk = blockIdx.x;
        for (int b = t; b < NB; b += 256) cur[b] = bBase[b] + BcntT[blk * NB + b];
        __syncthreads();
        for (int i = t; i < EC; i += 256) {
            int e = blk * EC + i;
            int r = rows[e];
            int p = atomicAdd(&cur[r >> 6], 1);   // LDS atomic
            ebuf[p] = make_uint2(((unsigned)(r & 63) << 20) | (unsigned)cols[e],
                                 (unsigned)__float_as_int(vals[e]));
        }
    } else {
        gemm_body<DIN, HID, false, false, true>(X, Wp0, bn0, ab0, bg0,
            nullptr, nullptr, nullptr, nullptr, Hn0b, Hgb, n, blockIdx.x - NCHK);
    }
}

template <int K, int HOUT, bool AFF, bool XBF, bool HNBF>
__global__ __launch_bounds__(256) void gemm_k(
    const void* __restrict__ X, const unsigned short* __restrict__ Wp,
    const float* __restrict__ bnA, const float* __restrict__ bnB, const float* __restrict__ bgA,
    const float* __restrict__ sums, const float* __restrict__ gamma, const float* __restrict__ beta,
    float* __restrict__ Hnf, unsigned short* __restrict__ Hnb, unsigned short* __restrict__ Hgb, int n)
{
    gemm_body<K, HOUT, AFF, XBF, HNBF>(X, Wp, bnA, bnB, bgA, sums, gamma, beta,
                                       Hnf, Hnb, Hgb, n, blockIdx.x);
}

// ---------------------------------------------------------------------------
// SpMM (row-sorted CSR gather): S[row] = Hn[row] + sum val*Hg[col], Hg bf16,
// register accumulation (NO atomics on the edge path).
// ---------------------------------------------------------------------------

template <int HH, bool STATS, bool SBF, bool MARKED>
__global__ __launch_bounds__(256) void spmm_k(
    const int* __restrict__ rowptr, const int2* __restrict__ cs,
    const unsigned short* __restrict__ Hgb, void* __restrict__ Sv,
    float* __restrict__ stats, const int* __restrict__ mark, int n)
{
    constexpr int L  = HH / 4;
    constexpr int GP = 256 / L;
    const int lane = threadIdx.x % L;
    const int g = threadIdx.x / L;
    const int gid = blockIdx.x * GP + g;
    const int ngroups = gridDim.x * GP;
    const int c0 = lane * 4;

    float4 sum = make_float4(0.f, 0.f, 0.f, 0.f);
    float4 sq  = make_float4(0.f, 0.f, 0.f, 0.f);
    for (int row = gid; row < n; row += ngroups) {
        if (MARKED && !mark[row]) continue;
        int e0 = rowptr[row], e1 = rowptr[row + 1];
        float4 a0, a1 = make_float4(0.f, 0.f, 0.f, 0.f);
        if (SBF) {
            uint2 h = *(const uint2*)((const unsigned short*)Sv + (size_t)row * HH + c0);
            a0 = make_float4(bf2f_lo(h.x), bf2f_hi(h.x), bf2f_lo(h.y), bf2f_hi(h.y));
        } else {
            a0 = *(const float4*)((const float*)Sv + (size_t)row * HH + c0);
        }
        int e = e0;
        for (; e + 1 < e1; e += 2) {
            int2 p0 = cs[e], p1 = cs[e + 1];
            float v0 = __int_as_float(p0.y), v1 = __int_as_float(p1.y);
            uint2 h0 = *(const uint2*)&Hgb[(size_t)p0.x * HH + c0];
            uint2 h1 = *(const uint2*)&Hgb[(size_t)p1.x * HH + c0];
            a0.x += v0 * bf2f_lo(h0.x); a0.y += v0 * bf2f_hi(h0.x);
            a0.z += v0 * bf2f_lo(h0.y); a0.w += v0 * bf2f_hi(h0.y);
            a1.x += v1 * bf2f_lo(h1.x); a1.y += v1 * bf2f_hi(h1.x);
            a1.z += v1 * bf2f_lo(h1.y); a1.w += v1 * bf2f_hi(h1.y);
        }
        if (e < e1) {
            int2 p = cs[e];
            float v = __int_as_float(p.y);
            uint2 h = *(const uint2*)&Hgb[(size_t)p.x * HH + c0];
            a0.x += v * bf2f_lo(h.x); a0.y += v * bf2f_hi(h.x);
            a0.z += v * bf2f_lo(h.y); a0.w += v * bf2f_hi(h.y);
        }
        float4 acc = make_float4(a0.x + a1.x, a0.y + a1.y, a0.z + a1.z, a0.w + a1.w);
        if (SBF) {
            uint2 o;
            o.x = (unsigned)f2bf(acc.x) | ((unsigned)f2bf(acc.y) << 16);
            o.y = (unsigned)f2bf(acc.z) | ((unsigned)f2bf(acc.w) << 16);
            *(uint2*)((unsigned short*)Sv + (size_t)row * HH + c0) = o;
        } else {
            *(float4*)((float*)Sv + (size_t)row * HH + c0) = acc;
        }
        if (STATS) {
            sum.x += acc.x; sum.y += acc.y; sum.z += acc.z; sum.w += acc.w;
            sq.x += acc.x * acc.x; sq.y += acc.y * acc.y;
            sq.z += acc.z * acc.z; sq.w += acc.w * acc.w;
        }
    }

    if constexpr (STATS) {
        __shared__ float rs[GP][HH];
        __shared__ float rq[GP][HH];
        *(float4*)&rs[g][c0] = sum;
        *(float4*)&rq[g][c0] = sq;
        __syncthreads();
        if (threadIdx.x < HH) {
            float a = 0.f, b = 0.f;
            for (int w = 0; w < GP; w++) { a += rs[w][threadIdx.x]; b += rq[w][threadIdx.x]; }
            int stripe = blockIdx.x & 7;
            atomicAdd(&stats[stripe * 128 + threadIdx.x], a);
            atomicAdd(&stats[stripe * 128 + HH + threadIdx.x], b);
        }
    }
}

__global__ void gather_k(const float* __restrict__ S, const int* __restrict__ idx,
                         float* __restrict__ out, int total4) {
    int j = blockIdx.x * 256 + threadIdx.x;
    if (j < total4) {
        int r = j / (EMB / 4), c4 = (j % (EMB / 4)) * 4;
        *(float4*)&out[(size_t)j * 4] = *(const float4*)&S[(size_t)idx[r] * EMB + c4];
    }
}

// ---------------------------------------------------------------------------

extern "C" void kernel_launch(void* const* d_in, const int* in_sizes, int n_in,
                              void* d_out, int out_size, void* d_ws, size_t ws_size,
                              hipStream_t stream) {
    const float* features = (const float*)d_in[0];
    const int*   rows     = (const int*)d_in[1];
    const int*   cols     = (const int*)d_in[2];
    const float* vals     = (const float*)d_in[3];
    const int*   idx      = (const int*)d_in[4];
    const float* Wn0 = (const float*)d_in[5];
    const float* bn0 = (const float*)d_in[6];
    const float* Wg0 = (const float*)d_in[7];
    const float* bg0 = (const float*)d_in[8];
    const float* ab0 = (const float*)d_in[9];
    const float* g0  = (const float*)d_in[10];
    const float* b0  = (const float*)d_in[11];
    const float* Wn1 = (const float*)d_in[12];
    const float* Wg1 = (const float*)d_in[13];
    const float* ab1 = (const float*)d_in[14];
    const float* g1  = (const float*)d_in[15];
    const float* b1  = (const float*)d_in[16];
    const float* WnL = (const float*)d_in[17];
    const float* WgL = (const float*)d_in[18];
    const float* abL = (const float*)d_in[19];
    float* out = (float*)d_out;

    // Workspace layout (~70 MB), 16B-aligned sub-buffers.
    float*          HnLf = (float*)d_ws;                        // N x EMB fp32 (HnL/SL)
    unsigned short* nA   = (unsigned short*)(HnLf + (size_t)NNODES * EMB); // Hn0/S0 bf16
    unsigned short* nB   = nA + (size_t)NNODES * HID;           // Hn1/S1 bf16
    unsigned short* Hgb  = nB + (size_t)NNODES * HID;           // Hg (all layers) bf16
    uint2* ebuf  = (uint2*)(Hgb + (size_t)NNODES * HID);        // E x 8B (packed)
    int2*  cs    = (int2*)(ebuf + NEDGES);                      // E (row-sorted payload)
    int*   rowptr = (int*)(cs + NEDGES);                        // N+4
    int*   Bcnt4 = rowptr + (NNODES + 4);                       // SUBC x NB
    int*   BcntT = Bcnt4 + SUBC * NB;                           // NCHK x NB
    int*   bTot  = BcntT + NCHK * NB;                           // NB (pad 1568)
    int*   bBase = bTot + 1568;                                 // NB+1 (pad 1568)
    unsigned short* Wp0 = (unsigned short*)(bBase + 1568);      // 16384
    unsigned short* Wp1 = Wp0 + 16384;                          // 8192
    unsigned short* WpL = Wp1 + 8192;                           // 4096
    // ---- single zeroed region: stats | mark ----
    float* stats = (float*)(WpL + 4096);                        // 2304
    int*   mark  = (int*)(stats + 2304);                        // N
    float* sums0 = stats;
    float* sums1 = stats + 1024;
    size_t zbytes = 2304 * 4 + (size_t)NNODES * 4;

    hipMemsetAsync(stats, 0, zbytes, stream);

    const int GBm = (NNODES + 63) / 64;     // 1563
    const int MB  = (NIDX + 255) / 256;     // 196

    // K1: bucket histogram + mark + W pre-pack (independent branches).
    histpack_k<<<SUBC + MB + 112, 256, 0, stream>>>(
        rows, Bcnt4, idx, mark, Wn0, Wg0, Wn1, Wg1, WnL, WgL, Wp0, Wp1, WpL, MB);
    bprefix_k<<<7, 256, 0, stream>>>(Bcnt4, BcntT, bTot);
    bscan_k<<<1, 256, 0, stream>>>(bTot, bBase);
    part_gemm0_k<<<NCHK + GBm, 256, 0, stream>>>(rows, cols, vals, BcntT, bBase, ebuf,
                                                 features, Wp0, bn0, ab0, bg0,
                                                 nA, Hgb, NNODES);
    bfinal_k<<<NB, 256, 0, stream>>>(ebuf, bBase, rowptr, cs);

    // Layer 0 aggregate: S0 = Hn0 + A@Hg0 (bf16 in/out, stats fp32)
    spmm_k<HID, true, true, false><<<1600, 256, 0, stream>>>(rowptr, cs, Hgb, nA, sums0, nullptr, NNODES);

    // Layer 1: BN finalize folded into gemm; S1 = Hn1 + ab1 + A@Hg1
    gemm_k<HID, HID, true, true, true><<<GBm, 256, 0, stream>>>(
        nA, Wp1, ab1, nullptr, nullptr, sums0, g0, b0, nullptr, nB, Hgb, NNODES);
    spmm_k<HID, true, true, false><<<1600, 256, 0, stream>>>(rowptr, cs, Hgb, nB, sums1, nullptr, NNODES);

    // Last layer: HnL fp32; aggregate only rows referenced by idx.
    gemm_k<HID, EMB, true, true, false><<<GBm, 256, 0, stream>>>(
        nB, WpL, abL, nullptr, nullptr, sums1, g1, b1, HnLf, nullptr, Hgb, NNODES);
    spmm_k<EMB, false, false, true><<<1600, 256, 0, stream>>>(rowptr, cs, Hgb, HnLf, nullptr, mark, NNODES);

    gather_k<<<(NIDX * EMB / 4 + 255) / 256, 256, 0, stream>>>(HnLf, idx, out, NIDX * EMB / 4);
}

// Round 12
// 276.970 us; speedup vs baseline: 3.2634x; 1.0202x over previous
//
#include <hip/hip_runtime.h>

// Problem constants (fixed by the reference).
#define NNODES 100000
#define NEDGES 800000
#define DIN    128
#define HID    64
#define EMB    32
#define NIDX   50000
#define BN_EPS 1e-5f

#define NCHK 256                  // partition chunks
#define EC   (NEDGES / NCHK)      // 3125 edges per chunk
#define SUBC 256                  // histogram sub-chunks (== NCHK)
#define ECS  (NEDGES / SUBC)      // 3125
#define NB   ((NNODES + 63) / 64) // 1563 row-buckets of 64 rows
#define HB   ((NB + 1) / 2)       // 782 buckets per partition half

typedef __attribute__((ext_vector_type(8))) short short8;   // 8 bf16 = 4 VGPR
typedef __attribute__((ext_vector_type(4))) float f32x4;    // MFMA C/D

__device__ inline unsigned short f2bf(float f) {            // RNE, matches HW
    unsigned u = __float_as_uint(f);
    unsigned r = u + 0x7FFFu + ((u >> 16) & 1u);
    return (unsigned short)(r >> 16);
}
__device__ inline float bf2f_lo(unsigned u) { return __uint_as_float(u << 16); }
__device__ inline float bf2f_hi(unsigned u) { return __uint_as_float(u & 0xffff0000u); }

// ---------------------------------------------------------------------------
// W pre-pack: fp32 [Wn|Wg] -> bf16 B-fragment-major (GEMM B-loads coalesced).
// ---------------------------------------------------------------------------

__device__ inline void pack_seg(const float* __restrict__ Wn, const float* __restrict__ Wg,
                                unsigned short* __restrict__ Wp, int HOUT, int l2nt, int f) {
    int j = f & 7, lane = (f >> 3) & 63, g = f >> 9;
    int tt = g & ((1 << l2nt) - 1), kb = g >> l2nt;
    int k = kb * 32 + ((lane >> 4) * 8) + j;
    int nn = tt * 16 + (lane & 15);
    float v = (nn < HOUT) ? Wn[k * HOUT + nn] : Wg[k * HOUT + (nn - HOUT)];
    Wp[f] = f2bf(v);
}

// ---------------------------------------------------------------------------
// K1: blocks [0,SUBC): bucket histogram -> Bcnt4[sub][b]
//     blocks [SUBC,SUBC+MB): mark[idx[j]] = 1
//     blocks [SUBC+MB,..): W pre-pack (all 3 layers)  -- all independent.
// ---------------------------------------------------------------------------

__global__ __launch_bounds__(256) void histpack_k(
    const int* __restrict__ rows, int* __restrict__ Bcnt4,
    const int* __restrict__ idx, int* __restrict__ mark,
    const float* Wn0, const float* Wg0, const float* Wn1,
    const float* Wg1, const float* WnL, const float* WgL,
    unsigned short* Wp0, unsigned short* Wp1, unsigned short* WpL, int MB)
{
    int blk = blockIdx.x;
    if (blk >= SUBC + MB) {
        int f = (blk - SUBC - MB) * 256 + threadIdx.x;
        if (f < 16384)      pack_seg(Wn0, Wg0, Wp0, 64, 3, f);           // 128x128
        else if (f < 24576) pack_seg(Wn1, Wg1, Wp1, 64, 3, f - 16384);   // 64x128
        else if (f < 28672) pack_seg(WnL, WgL, WpL, 32, 2, f - 24576);   // 64x64
        return;
    }
    if (blk >= SUBC) {
        int j = (blk - SUBC) * 256 + threadIdx.x;
        if (j < NIDX) mark[idx[j]] = 1;
        return;
    }
    __shared__ int hist[NB];
    int t = threadIdx.x;
    for (int b = t; b < NB; b += 256) hist[b] = 0;
    __syncthreads();
    for (int i = t; i < ECS; i += 256)
        atomicAdd(&hist[rows[blk * ECS + i] >> 6], 1);
    __syncthreads();
    for (int b = t; b < NB; b += 256) Bcnt4[blk * NB + b] = hist[b];
}

__global__ void bprefix_k(const int* __restrict__ Bcnt4, int* __restrict__ BcntT,
                          int* __restrict__ bTot) {
    int b = blockIdx.x * 256 + threadIdx.x;
    if (b >= NB) return;
    int run = 0;
    for (int sub = 0; sub < SUBC; sub++) {
        BcntT[sub * NB + b] = run;       // coalesced read & write
        run += Bcnt4[sub * NB + b];
    }
    bTot[b] = run;
}

__global__ void bscan_k(const int* __restrict__ bTot, int* __restrict__ bBase) {
    __shared__ int s[256];
    int t = threadIdx.x;
    int v[7], loc = 0;
#pragma unroll
    for (int i = 0; i < 7; i++) {
        int ix = t * 7 + i;
        v[i] = loc;
        loc += (ix < NB) ? bTot[ix] : 0;
    }
    s[t] = loc;
    __syncthreads();
    for (int off = 1; off < 256; off <<= 1) {
        int a = (t >= off) ? s[t - off] : 0;
        __syncthreads();
        s[t] += a;
        __syncthreads();
    }
    int base = s[t] - loc;
#pragma unroll
    for (int i = 0; i < 7; i++) {
        int ix = t * 7 + i;
        if (ix < NB) bBase[ix] = base + v[i];
    }
    if (t == 255) bBase[NB] = NEDGES;
}

// bfinal: one block per bucket (64 rows, ~512 edges): LDS 64-bin hist + scan
//         -> rowptr; scatter {col,val} into final row-sorted cs.
// ebuf entry: x = (row&63)<<20 | col, y = val bits  (8 B/edge).
__global__ __launch_bounds__(256) void bfinal_k(const uint2* __restrict__ ebuf,
                                                const int* __restrict__ bBase,
                                                int* __restrict__ rowptr,
                                                int2* __restrict__ cs) {
    __shared__ int hist[64], sc[64], cur[64];
    int b = blockIdx.x, t = threadIdx.x;
    int e0 = bBase[b], e1 = bBase[b + 1];
    int r0 = b << 6;
    if (t < 64) hist[t] = 0;
    __syncthreads();
    for (int i = e0 + t; i < e1; i += 256)
        atomicAdd(&hist[(ebuf[i].x >> 20) & 63], 1);
    __syncthreads();
    if (t == 0) {
        int run = e0;
        for (int j = 0; j < 64; j++) { sc[j] = run; run += hist[j]; }
    }
    __syncthreads();
    if (t < 64) {
        cur[t] = sc[t];
        int r = r0 + t;
        if (r < NNODES) rowptr[r] = sc[t];
    }
    if (b == NB - 1 && t == 0) rowptr[NNODES] = NEDGES;
    __syncthreads();
    for (int i = e0 + t; i < e1; i += 256) {
        uint2 v = ebuf[i];
        int p = atomicAdd(&cur[(v.x >> 20) & 63], 1);
        cs[p] = make_int2((int)(v.x & 0xFFFFF), (int)v.y);
    }
}

// ---------------------------------------------------------------------------
// MFMA dual-GEMM body. [Hn | Hg] = act(X) @ [Wn | Wg] (+ per-col biases);
// Hg always bf16 out; Hn bf16 (HNBF) or fp32. X fp32 or bf16 (XBF).
// AFF: BN scale/shift recomputed in-block from striped sums.
// ---------------------------------------------------------------------------

template <int K, int HOUT, bool AFF, bool XBF, bool HNBF>
__device__ void gemm_body(const void* __restrict__ Xv, const unsigned short* __restrict__ Wp,
                          const float* __restrict__ bnA, const float* __restrict__ bnB,
                          const float* __restrict__ bgA,
                          const float* __restrict__ sums, const float* __restrict__ gamma,
                          const float* __restrict__ beta,
                          float* __restrict__ Hnf, unsigned short* __restrict__ Hnb,
                          unsigned short* __restrict__ Hgb, int n, int blk)
{
    constexpr int NT = 2 * HOUT / 16, NKB = K / 32;
    constexpr int RS = K + 8;
    __shared__ unsigned short Xs[64 * RS];
    __shared__ float sSc[64], sSh[64];

    const int row0 = blk * 64;
    const int t = threadIdx.x;

    if (AFF) {               // in-block BN finalize: 1KB of reads, once per block
        if (t < 64) {
            float sum = 0.f, sq = 0.f;
#pragma unroll
            for (int s = 0; s < 8; s++) { sum += sums[s * 128 + t]; sq += sums[s * 128 + 64 + t]; }
            float m = sum / (float)NNODES;
            float var = sq / (float)NNODES - m * m;
            float sc = gamma[t] * rsqrtf(var + BN_EPS);
            sSc[t] = sc; sSh[t] = beta[t] - m * sc;
        }
        __syncthreads();
    }

    // Stage 64 x K -> bf16 LDS, 8 k-cols per step (affine+relu on the fly).
    for (int li = t; li < 64 * K / 8; li += 256) {
        int r  = li / (K / 8);
        int k8 = (li % (K / 8)) * 8;
        int rr = row0 + r;
        float v[8];
        if (XBF) {
            uint4 u = (rr < n) ? *(const uint4*)((const unsigned short*)Xv + (size_t)rr * K + k8)
                               : make_uint4(0, 0, 0, 0);
            v[0] = bf2f_lo(u.x); v[1] = bf2f_hi(u.x);
            v[2] = bf2f_lo(u.y); v[3] = bf2f_hi(u.y);
            v[4] = bf2f_lo(u.z); v[5] = bf2f_hi(u.z);
            v[6] = bf2f_lo(u.w); v[7] = bf2f_hi(u.w);
        } else {
            const float* Xf = (const float*)Xv;
            float4 a = make_float4(0.f, 0.f, 0.f, 0.f), b = a;
            if (rr < n) {
                a = *(const float4*)&Xf[(size_t)rr * K + k8];
                b = *(const float4*)&Xf[(size_t)rr * K + k8 + 4];
            }
            v[0] = a.x; v[1] = a.y; v[2] = a.z; v[3] = a.w;
            v[4] = b.x; v[5] = b.y; v[6] = b.z; v[7] = b.w;
        }
        if (AFF) {
#pragma unroll
            for (int i = 0; i < 8; i++) v[i] = fmaxf(v[i] * sSc[k8 + i] + sSh[k8 + i], 0.f);
        }
        uint4 o;
        o.x = (unsigned)f2bf(v[0]) | ((unsigned)f2bf(v[1]) << 16);
        o.y = (unsigned)f2bf(v[2]) | ((unsigned)f2bf(v[3]) << 16);
        o.z = (unsigned)f2bf(v[4]) | ((unsigned)f2bf(v[5]) << 16);
        o.w = (unsigned)f2bf(v[6]) | ((unsigned)f2bf(v[7]) << 16);
        *(uint4*)&Xs[r * RS + k8] = o;
    }
    __syncthreads();

    const int wave = t >> 6, lane = t & 63;
    const int q = lane >> 4, mrow = lane & 15;

    f32x4 acc[NT];
#pragma unroll
    for (int i = 0; i < NT; i++) acc[i] = (f32x4){0.f, 0.f, 0.f, 0.f};

    const short8* wp8 = (const short8*)Wp;
#pragma unroll
    for (int kb = 0; kb < NKB; kb++) {
        short8 a = *(const short8*)&Xs[(wave * 16 + mrow) * RS + kb * 32 + q * 8];
#pragma unroll
        for (int tt = 0; tt < NT; tt++) {
            short8 b = wp8[(kb * NT + tt) * 64 + lane];   // coalesced dwordx4
            acc[tt] = __builtin_amdgcn_mfma_f32_16x16x32_bf16(a, b, acc[tt], 0, 0, 0);
        }
    }

    // Epilogue. C/D: col = lane&15 (tile tt), row = q*4 + reg.
#pragma unroll
    for (int tt = 0; tt < NT; tt++) {
        int nglob = tt * 16 + mrow;
        bool nside = (nglob < HOUT);
        int c = nside ? nglob : (nglob - HOUT);
        float bias = 0.f;
        if (nside) {
            if (bnA) bias += bnA[c];
            if (bnB) bias += bnB[c];
        } else if (bgA) {
            bias += bgA[c];
        }
#pragma unroll
        for (int r = 0; r < 4; r++) {
            int rr = row0 + wave * 16 + q * 4 + r;
            if (rr < n) {
                float o = acc[tt][r] + bias;
                if (nside) {
                    if (HNBF) Hnb[(size_t)rr * HOUT + c] = f2bf(o);
                    else      Hnf[(size_t)rr * HOUT + c] = o;
                } else {
                    Hgb[(size_t)rr * HOUT + c] = f2bf(o);
                }
            }
        }
    }
}

// K_C: blocks [0,2*NCHK): bucket-partition. Each chunk is handled by TWO
//      blocks (half = blk&1, buckets [half*HB,...)): 2x scatter parallelism
//      with UNCHANGED (chunk,bucket) run lengths (write-amp constant).
//      blocks [2*NCHK,..): layer-0 dual GEMM (co-scheduled, independent).
__global__ __launch_bounds__(256) void part_gemm0_k(
    const int* __restrict__ rows, const int* __restrict__ cols,
    const float* __restrict__ vals, const int* __restrict__ BcntT,
    const int* __restrict__ bBase, uint2* __restrict__ ebuf,
    const float* __restrict__ X, const unsigned short* __restrict__ Wp0,
    const float* __restrict__ bn0, const float* __restrict__ ab0, const float* __restrict__ bg0,
    unsigned short* __restrict__ Hn0b, unsigned short* __restrict__ Hgb, int n)
{
    if ((int)blockIdx.x < 2 * NCHK) {
        __shared__ int cur[HB];
        int t = threadIdx.x;
        int blk = blockIdx.x >> 1, half = blockIdx.x & 1;
        int b0 = half * HB, b1 = (half ? NB : HB);
        for (int b = b0 + t; b < b1; b += 256)
            cur[b - b0] = bBase[b] + BcntT[blk * NB + b];
        __syncthreads();
        for (int i = t; i < EC; i += 256) {
            int e = blk * EC + i;
            int r = rows[e];
            int b = r >> 6;
            if (b < b0 || b >= b1) continue;       // other half's edge
            int p = atomicAdd(&cur[b - b0], 1);    // LDS atomic
            ebuf[p] = make_uint2(((unsigned)(r & 63) << 20) | (unsigned)cols[e],
                                 (unsigned)__float_as_int(vals[e]));
        }
    } else {
        gemm_body<DIN, HID, false, false, true>(X, Wp0, bn0, ab0, bg0,
            nullptr, nullptr, nullptr, nullptr, Hn0b, Hgb, n, blockIdx.x - 2 * NCHK);
    }
}

template <int K, int HOUT, bool AFF, bool XBF, bool HNBF>
__global__ __launch_bounds__(256) void gemm_k(
    const void* __restrict__ X, const unsigned short* __restrict__ Wp,
    const float* __restrict__ bnA, const float* __restrict__ bnB, const float* __restrict__ bgA,
    const float* __restrict__ sums, const float* __restrict__ gamma, const float* __restrict__ beta,
    float* __restrict__ Hnf, unsigned short* __restrict__ Hnb, unsigned short* __restrict__ Hgb, int n)
{
    gemm_body<K, HOUT, AFF, XBF, HNBF>(X, Wp, bnA, bnB, bgA, sums, gamma, beta,
                                       Hnf, Hnb, Hgb, n, blockIdx.x);
}

// ---------------------------------------------------------------------------
// SpMM (row-sorted CSR gather): S[row] = Hn[row] + sum val*Hg[col], Hg bf16,
// register accumulation, 4-way unroll (4 outstanding L2/L3 gathers per group).
// ---------------------------------------------------------------------------

template <int HH, bool STATS, bool SBF, bool MARKED>
__global__ __launch_bounds__(256) void spmm_k(
    const int* __restrict__ rowptr, const int2* __restrict__ cs,
    const unsigned short* __restrict__ Hgb, void* __restrict__ Sv,
    float* __restrict__ stats, const int* __restrict__ mark, int n)
{
    constexpr int L  = HH / 4;
    constexpr int GP = 256 / L;
    const int lane = threadIdx.x % L;
    const int g = threadIdx.x / L;
    const int gid = blockIdx.x * GP + g;
    const int ngroups = gridDim.x * GP;
    const int c0 = lane * 4;

    float4 sum = make_float4(0.f, 0.f, 0.f, 0.f);
    float4 sq  = make_float4(0.f, 0.f, 0.f, 0.f);
    for (int row = gid; row < n; row += ngroups) {
        if (MARKED && !mark[row]) continue;
        int e0 = rowptr[row], e1 = rowptr[row + 1];
        float4 a0, a1, a2, a3;
        if (SBF) {
            uint2 h = *(const uint2*)((const unsigned short*)Sv + (size_t)row * HH + c0);
            a0 = make_float4(bf2f_lo(h.x), bf2f_hi(h.x), bf2f_lo(h.y), bf2f_hi(h.y));
        } else {
            a0 = *(const float4*)((const float*)Sv + (size_t)row * HH + c0);
        }
        a1 = a2 = a3 = make_float4(0.f, 0.f, 0.f, 0.f);
        int e = e0;
        for (; e + 3 < e1; e += 4) {               // 4 independent gather chains
            int2 p0 = cs[e], p1 = cs[e + 1], p2 = cs[e + 2], p3 = cs[e + 3];
            float v0 = __int_as_float(p0.y), v1 = __int_as_float(p1.y);
            float v2 = __int_as_float(p2.y), v3 = __int_as_float(p3.y);
            uint2 h0 = *(const uint2*)&Hgb[(size_t)p0.x * HH + c0];
            uint2 h1 = *(const uint2*)&Hgb[(size_t)p1.x * HH + c0];
            uint2 h2 = *(const uint2*)&Hgb[(size_t)p2.x * HH + c0];
            uint2 h3 = *(const uint2*)&Hgb[(size_t)p3.x * HH + c0];
            a0.x += v0 * bf2f_lo(h0.x); a0.y += v0 * bf2f_hi(h0.x);
            a0.z += v0 * bf2f_lo(h0.y); a0.w += v0 * bf2f_hi(h0.y);
            a1.x += v1 * bf2f_lo(h1.x); a1.y += v1 * bf2f_hi(h1.x);
            a1.z += v1 * bf2f_lo(h1.y); a1.w += v1 * bf2f_hi(h1.y);
            a2.x += v2 * bf2f_lo(h2.x); a2.y += v2 * bf2f_hi(h2.x);
            a2.z += v2 * bf2f_lo(h2.y); a2.w += v2 * bf2f_hi(h2.y);
            a3.x += v3 * bf2f_lo(h3.x); a3.y += v3 * bf2f_hi(h3.x);
            a3.z += v3 * bf2f_lo(h3.y); a3.w += v3 * bf2f_hi(h3.y);
        }
        for (; e < e1; e++) {
            int2 p = cs[e];
            float v = __int_as_float(p.y);
            uint2 h = *(const uint2*)&Hgb[(size_t)p.x * HH + c0];
            a0.x += v * bf2f_lo(h.x); a0.y += v * bf2f_hi(h.x);
            a0.z += v * bf2f_lo(h.y); a0.w += v * bf2f_hi(h.y);
        }
        float4 acc = make_float4(a0.x + a1.x + a2.x + a3.x, a0.y + a1.y + a2.y + a3.y,
                                 a0.z + a1.z + a2.z + a3.z, a0.w + a1.w + a2.w + a3.w);
        if (SBF) {
            uint2 o;
            o.x = (unsigned)f2bf(acc.x) | ((unsigned)f2bf(acc.y) << 16);
            o.y = (unsigned)f2bf(acc.z) | ((unsigned)f2bf(acc.w) << 16);
            *(uint2*)((unsigned short*)Sv + (size_t)row * HH + c0) = o;
        } else {
            *(float4*)((float*)Sv + (size_t)row * HH + c0) = acc;
        }
        if (STATS) {
            sum.x += acc.x; sum.y += acc.y; sum.z += acc.z; sum.w += acc.w;
            sq.x += acc.x * acc.x; sq.y += acc.y * acc.y;
            sq.z += acc.z * acc.z; sq.w += acc.w * acc.w;
        }
    }

    if constexpr (STATS) {
        __shared__ float rs[GP][HH];
        __shared__ float rq[GP][HH];
        *(float4*)&rs[g][c0] = sum;
        *(float4*)&rq[g][c0] = sq;
        __syncthreads();
        if (threadIdx.x < HH) {
            float a = 0.f, b = 0.f;
            for (int w = 0; w < GP; w++) { a += rs[w][threadIdx.x]; b += rq[w][threadIdx.x]; }
            int stripe = blockIdx.x & 7;
            atomicAdd(&stats[stripe * 128 + threadIdx.x], a);
            atomicAdd(&stats[stripe * 128 + HH + threadIdx.x], b);
        }
    }
}

__global__ void gather_k(const float* __restrict__ S, const int* __restrict__ idx,
                         float* __restrict__ out, int total4) {
    int j = blockIdx.x * 256 + threadIdx.x;
    if (j < total4) {
        int r = j / (EMB / 4), c4 = (j % (EMB / 4)) * 4;
        *(float4*)&out[(size_t)j * 4] = *(const float4*)&S[(size_t)idx[r] * EMB + c4];
    }
}

// ---------------------------------------------------------------------------

extern "C" void kernel_launch(void* const* d_in, const int* in_sizes, int n_in,
                              void* d_out, int out_size, void* d_ws, size_t ws_size,
                              hipStream_t stream) {
    const float* features = (const float*)d_in[0];
    const int*   rows     = (const int*)d_in[1];
    const int*   cols     = (const int*)d_in[2];
    const float* vals     = (const float*)d_in[3];
    const int*   idx      = (const int*)d_in[4];
    const float* Wn0 = (const float*)d_in[5];
    const float* bn0 = (const float*)d_in[6];
    const float* Wg0 = (const float*)d_in[7];
    const float* bg0 = (const float*)d_in[8];
    const float* ab0 = (const float*)d_in[9];
    const float* g0  = (const float*)d_in[10];
    const float* b0  = (const float*)d_in[11];
    const float* Wn1 = (const float*)d_in[12];
    const float* Wg1 = (const float*)d_in[13];
    const float* ab1 = (const float*)d_in[14];
    const float* g1  = (const float*)d_in[15];
    const float* b1  = (const float*)d_in[16];
    const float* WnL = (const float*)d_in[17];
    const float* WgL = (const float*)d_in[18];
    const float* abL = (const float*)d_in[19];
    float* out = (float*)d_out;

    // Workspace layout (~70 MB), 16B-aligned sub-buffers.
    float*          HnLf = (float*)d_ws;                        // N x EMB fp32 (HnL/SL)
    unsigned short* nA   = (unsigned short*)(HnLf + (size_t)NNODES * EMB); // Hn0/S0 bf16
    unsigned short* nB   = nA + (size_t)NNODES * HID;           // Hn1/S1 bf16
    unsigned short* Hgb  = nB + (size_t)NNODES * HID;           // Hg (all layers) bf16
    uint2* ebuf  = (uint2*)(Hgb + (size_t)NNODES * HID);        // E x 8B (packed)
    int2*  cs    = (int2*)(ebuf + NEDGES);                      // E (row-sorted payload)
    int*   rowptr = (int*)(cs + NEDGES);                        // N+4
    int*   Bcnt4 = rowptr + (NNODES + 4);                       // SUBC x NB
    int*   BcntT = Bcnt4 + SUBC * NB;                           // NCHK x NB
    int*   bTot  = BcntT + NCHK * NB;                           // NB (pad 1568)
    int*   bBase = bTot + 1568;                                 // NB+1 (pad 1568)
    unsigned short* Wp0 = (unsigned short*)(bBase + 1568);      // 16384
    unsigned short* Wp1 = Wp0 + 16384;                          // 8192
    unsigned short* WpL = Wp1 + 8192;                           // 4096
    // ---- single zeroed region: stats | mark ----
    float* stats = (float*)(WpL + 4096);                        // 2304
    int*   mark  = (int*)(stats + 2304);                        // N
    float* sums0 = stats;
    float* sums1 = stats + 1024;
    size_t zbytes = 2304 * 4 + (size_t)NNODES * 4;

    hipMemsetAsync(stats, 0, zbytes, stream);

    const int GBm = (NNODES + 63) / 64;     // 1563
    const int MB  = (NIDX + 255) / 256;     // 196

    // K1: bucket histogram + mark + W pre-pack (independent branches).
    histpack_k<<<SUBC + MB + 112, 256, 0, stream>>>(
        rows, Bcnt4, idx, mark, Wn0, Wg0, Wn1, Wg1, WnL, WgL, Wp0, Wp1, WpL, MB);
    bprefix_k<<<7, 256, 0, stream>>>(Bcnt4, BcntT, bTot);
    bscan_k<<<1, 256, 0, stream>>>(bTot, bBase);
    part_gemm0_k<<<2 * NCHK + GBm, 256, 0, stream>>>(rows, cols, vals, BcntT, bBase, ebuf,
                                                     features, Wp0, bn0, ab0, bg0,
                                                     nA, Hgb, NNODES);
    bfinal_k<<<NB, 256, 0, stream>>>(ebuf, bBase, rowptr, cs);

    // Layer 0 aggregate: S0 = Hn0 + A@Hg0 (bf16 in/out, stats fp32)
    spmm_k<HID, true, true, false><<<1600, 256, 0, stream>>>(rowptr, cs, Hgb, nA, sums0, nullptr, NNODES);

    // Layer 1: BN finalize folded into gemm; S1 = Hn1 + ab1 + A@Hg1
    gemm_k<HID, HID, true, true, true><<<GBm, 256, 0, stream>>>(
        nA, Wp1, ab1, nullptr, nullptr, sums0, g0, b0, nullptr, nB, Hgb, NNODES);
    spmm_k<HID, true, true, false><<<1600, 256, 0, stream>>>(rowptr, cs, Hgb, nB, sums1, nullptr, NNODES);

    // Last layer: HnL fp32; aggregate only rows referenced by idx.
    gemm_k<HID, EMB, true, true, false><<<GBm, 256, 0, stream>>>(
        nB, WpL, abL, nullptr, nullptr, sums1, g1, b1, HnLf, nullptr, Hgb, NNODES);
    spmm_k<EMB, false, false, true><<<1600, 256, 0, stream>>>(rowptr, cs, Hgb, HnLf, nullptr, mark, NNODES);

    gather_k<<<(NIDX * EMB / 4 + 255) / 256, 256, 0, stream>>>(HnLf, idx, out, NIDX * EMB / 4);
}